// Round 11
// baseline (743.608 us; speedup 1.0000x reference)
//
#include <hip/hip_runtime.h>

#define N_FEAT 50
#define HID 16
#define NC 10
#define TPB 256
#define GRID 512
#define DEGB 128          // blocks doing deg in P2; the rest do node1

#define NPB 128           // nodes per bucket
#define NPB_SHIFT 7
#define NPB_MASK 127
#define CAP 2560          // edges per bucket capacity (mean 2046, +11 sigma)
#define NBK 800           // bucket-count capacity (actual NB = 782)
#define WSTR 52           // padded transposed-weight row stride

#define SCALE1 4194304.0f         // 2^22
#define INV1   (1.0f/4194304.0f)
#define SCALE2 2097152.0f         // 2^21
#define INV2   (1.0f/2097152.0f)

__device__ __forceinline__ unsigned short f2bf(float f) {
    unsigned u = __float_as_uint(f);
    u += 0x7FFFu + ((u >> 16) & 1u);
    return (unsigned short)(u >> 16);
}
__device__ __forceinline__ unsigned packbf(float lo, float hi) {
    return (unsigned)f2bf(lo) | ((unsigned)f2bf(hi) << 16);
}

union SmemU {
    int   acc[NPB * 17];                       // P3/P4 accumulators
    float swT[2][HID * WSTR];                  // P2 node1 weights
    struct { int hist[NBK]; int base[NBK]; } bin;  // P1
    int   dhist[NPB];                          // P2 deg
};

// software grid barrier: monotonic counter, agent-scope acq/rel, bounded spin
__device__ __forceinline__ void gridbar(int* bar, int target) {
    __syncthreads();
    if (threadIdx.x == 0) {
        __threadfence();   // release: drain + cross-XCD L2 writeback
        __hip_atomic_fetch_add(bar, 1, __ATOMIC_ACQ_REL, __HIP_MEMORY_SCOPE_AGENT);
        int spins = 0;
        while (__hip_atomic_load(bar, __ATOMIC_ACQUIRE, __HIP_MEMORY_SCOPE_AGENT) < target) {
            __builtin_amdgcn_s_sleep(8);
            if (++spins > (1 << 20)) break;    // bail instead of hanging
        }
        __threadfence();   // acquire: invalidate stale L1/L2
    }
    __syncthreads();
}

// one edge: load bf16x8 half-message of src, scale by dinv[src]*S, fixed-point LDS adds
__device__ __forceinline__ void agg_edge(int* acc, int w, const uint4* __restrict__ msg,
                                         const float* __restrict__ dinv, int q, float S) {
    int s = w >> NPB_SHIFT;
    uint4 m = msg[(size_t)s * 2 + q];
    float f = dinv[s] * S;
    int base = (w & NPB_MASK) * 17 + q * 8;
    atomicAdd(&acc[base + 0], __float2int_rn(__uint_as_float(m.x << 16) * f));
    atomicAdd(&acc[base + 1], __float2int_rn(__uint_as_float(m.x & 0xFFFF0000u) * f));
    atomicAdd(&acc[base + 2], __float2int_rn(__uint_as_float(m.y << 16) * f));
    atomicAdd(&acc[base + 3], __float2int_rn(__uint_as_float(m.y & 0xFFFF0000u) * f));
    atomicAdd(&acc[base + 4], __float2int_rn(__uint_as_float(m.z << 16) * f));
    atomicAdd(&acc[base + 5], __float2int_rn(__uint_as_float(m.z & 0xFFFF0000u) * f));
    atomicAdd(&acc[base + 6], __float2int_rn(__uint_as_float(m.w << 16) * f));
    atomicAdd(&acc[base + 7], __float2int_rn(__uint_as_float(m.w & 0xFFFF0000u) * f));
}

__global__ __launch_bounds__(TPB, 2)
void mega_kernel(const float* __restrict__ x,
                 const int* __restrict__ src, const int* __restrict__ dst,
                 const float* __restrict__ w10, const float* __restrict__ w11,
                 const float* __restrict__ b1,
                 const float* __restrict__ w20, const float* __restrict__ w21,
                 const float* __restrict__ b2,
                 int n, int E, int NB,
                 int* __restrict__ bar, int* __restrict__ bcur, int* __restrict__ ebuf,
                 float* __restrict__ dinv,
                 float* __restrict__ s1, uint4* __restrict__ u1,
                 float* __restrict__ s2p12, uint4* __restrict__ u2,
                 float* __restrict__ out)
{
    __shared__ SmemU u;
    __shared__ float sw0[HID * NC], sw1[HID * NC], sb1[HID], sb2[NC];

    int t = threadIdx.x;
    if (t < HID * NC) { sw0[t] = w20[t]; sw1[t] = w21[t]; }
    if (t < HID) sb1[t] = b1[t];
    if (t < NC) sb2[t] = b2[t];

    // ---- P1: bin edges -> bucket-contiguous packed words (2-pass LDS hist) ----
    {
        int chunk = (E + GRID - 1) / GRID;
        int e0 = blockIdx.x * chunk;
        int e1 = e0 + chunk; if (e1 > E) e1 = E;
        for (int i = t; i < NB; i += TPB) u.bin.hist[i] = 0;
        __syncthreads();
        for (int e = e0 + t; e < e1; e += TPB)
            atomicAdd(&u.bin.hist[dst[e] >> NPB_SHIFT], 1);
        __syncthreads();
        for (int b = t; b < NB; b += TPB) {
            int c = u.bin.hist[b];
            u.bin.base[b] = (c > 0) ? atomicAdd(&bcur[b * 16], c) : 0;
            u.bin.hist[b] = 0;
        }
        __syncthreads();
        for (int e = e0 + t; e < e1; e += TPB) {
            int d = dst[e];
            int s = src[e];
            int b = d >> NPB_SHIFT;
            int off = atomicAdd(&u.bin.hist[b], 1);
            int pos = u.bin.base[b] + off;
            if (pos < CAP)
                ebuf[b * CAP + pos] = (s << NPB_SHIFT) | (d & NPB_MASK);
        }
    }
    gridbar(bar, GRID);

    // ---- P2: deg->dinv (blocks < DEGB)  ||  node1 (the rest) ----
    if (blockIdx.x < DEGB) {
        for (int j = blockIdx.x; j < NB; j += DEGB) {
            int cnt = bcur[j * 16]; if (cnt > CAP) cnt = CAP;
            if (t < NPB) u.dhist[t] = 0;
            __syncthreads();
            for (int k = t; k < cnt; k += TPB)
                atomicAdd(&u.dhist[ebuf[j * CAP + k] & NPB_MASK], 1);
            __syncthreads();
            int node = j * NPB + t;
            if (t < NPB && node < n) {
                int dg = u.dhist[t];
                dinv[node] = dg > 0 ? rsqrtf((float)dg) : 0.f;
            }
            __syncthreads();
        }
    } else {
        float* swT0 = u.swT[0];
        float* swT1 = u.swT[1];
        for (int i = t; i < 2 * HID * WSTR; i += TPB) ((float*)u.swT)[i] = 0.f;
        __syncthreads();
        for (int idx = t; idx < N_FEAT * HID; idx += TPB) {
            int i = idx >> 4, j = idx & 15;
            swT0[j * WSTR + i] = w10[idx];
            swT1[j * WSTR + i] = w11[idx];
        }
        __syncthreads();
        int nch = (n + TPB - 1) / TPB;
        for (int c = blockIdx.x - DEGB; c < nch; c += GRID - DEGB) {
            int node = c * TPB + t;
            if (node >= n) continue;
            float xr[52];
            const float2* xp = (const float2*)(x + (size_t)node * N_FEAT);
#pragma unroll
            for (int i = 0; i < 25; i++) { float2 v = xp[i]; xr[2*i] = v.x; xr[2*i+1] = v.y; }
            xr[50] = 0.f; xr[51] = 0.f;
            float so[HID], po[HID];
#pragma unroll
            for (int j = 0; j < HID; j++) {
                float a0 = 0.f, a1 = 0.f;
#pragma unroll
                for (int i4 = 0; i4 < 13; i4++) {
                    float4 wv0 = *(const float4*)&swT0[j * WSTR + i4 * 4];
                    float4 wv1 = *(const float4*)&swT1[j * WSTR + i4 * 4];
                    a0 += xr[i4*4+0]*wv0.x + xr[i4*4+1]*wv0.y + xr[i4*4+2]*wv0.z + xr[i4*4+3]*wv0.w;
                    a1 += xr[i4*4+0]*wv1.x + xr[i4*4+1]*wv1.y + xr[i4*4+2]*wv1.z + xr[i4*4+3]*wv1.w;
                }
                so[j] = a0; po[j] = a1;          // po UNSCALED (dinv applied per-edge)
            }
            float4* s1p = (float4*)(s1 + (size_t)node * HID);
#pragma unroll
            for (int i = 0; i < 4; i++)
                s1p[i] = make_float4(so[4*i], so[4*i+1], so[4*i+2], so[4*i+3]);
            u1[(size_t)node * 2 + 0] = make_uint4(packbf(po[0], po[1]), packbf(po[2], po[3]),
                                                  packbf(po[4], po[5]), packbf(po[6], po[7]));
            u1[(size_t)node * 2 + 1] = make_uint4(packbf(po[8], po[9]), packbf(po[10], po[11]),
                                                  packbf(po[12], po[13]), packbf(po[14], po[15]));
        }
    }
    gridbar(bar, 2 * GRID);

    // ---- P3: agg layer-1 (int LDS atomics) + node2 epilogue ----
    for (int j = blockIdx.x; j < NB; j += GRID) {
        int cnt = bcur[j * 16]; if (cnt > CAP) cnt = CAP;
        for (int i = t; i < NPB * 17; i += TPB) u.acc[i] = 0;
        __syncthreads();
        int q = t & 1;
        int k = t >> 1;
        const int* eb = ebuf + j * CAP;
        for (; k + TPB / 2 < cnt; k += TPB) {
            agg_edge(u.acc, eb[k], u1, dinv, q, SCALE1);
            agg_edge(u.acc, eb[k + TPB / 2], u1, dinv, q, SCALE1);
        }
        for (; k < cnt; k += TPB / 2)
            agg_edge(u.acc, eb[k], u1, dinv, q, SCALE1);
        __syncthreads();
        int node = j * NPB + t;
        if (t < NPB && node < n) {
            float di = dinv[node];
            const int* ar = &u.acc[t * 17];
            float h[HID];
            const float4* sp = (const float4*)(s1 + (size_t)node * HID);
#pragma unroll
            for (int i = 0; i < 4; i++) {
                float4 sv = sp[i];
                h[4*i+0] = fmaxf(sv.x + di * ((float)ar[4*i+0] * INV1) + sb1[4*i+0], 0.f);
                h[4*i+1] = fmaxf(sv.y + di * ((float)ar[4*i+1] * INV1) + sb1[4*i+1], 0.f);
                h[4*i+2] = fmaxf(sv.z + di * ((float)ar[4*i+2] * INV1) + sb1[4*i+2], 0.f);
                h[4*i+3] = fmaxf(sv.w + di * ((float)ar[4*i+3] * INV1) + sb1[4*i+3], 0.f);
            }
            float so2[12], po2[NC];
#pragma unroll
            for (int c = 0; c < NC; c++) {
                float a0 = 0.f, a1 = 0.f;
#pragma unroll
                for (int jj = 0; jj < HID; jj++) {
                    a0 += h[jj] * sw0[jj * NC + c];
                    a1 += h[jj] * sw1[jj * NC + c];
                }
                so2[c] = a0; po2[c] = a1;        // UNSCALED
            }
            so2[10] = 0.f; so2[11] = 0.f;
            float4* s2v = (float4*)(s2p12 + (size_t)node * 12);
#pragma unroll
            for (int i = 0; i < 3; i++)
                s2v[i] = make_float4(so2[4*i], so2[4*i+1], so2[4*i+2], so2[4*i+3]);
            u2[(size_t)node * 2 + 0] = make_uint4(packbf(po2[0], po2[1]), packbf(po2[2], po2[3]),
                                                  packbf(po2[4], po2[5]), packbf(po2[6], po2[7]));
            u2[(size_t)node * 2 + 1] = make_uint4(packbf(po2[8], po2[9]), 0u, 0u, 0u);
        }
        __syncthreads();
    }
    gridbar(bar, 3 * GRID);

    // ---- P4: agg layer-2 + log_softmax ----
    for (int j = blockIdx.x; j < NB; j += GRID) {
        int cnt = bcur[j * 16]; if (cnt > CAP) cnt = CAP;
        for (int i = t; i < NPB * 17; i += TPB) u.acc[i] = 0;
        __syncthreads();
        int q = t & 1;
        int k = t >> 1;
        const int* eb = ebuf + j * CAP;
        for (; k + TPB / 2 < cnt; k += TPB) {
            agg_edge(u.acc, eb[k], u2, dinv, q, SCALE2);
            agg_edge(u.acc, eb[k + TPB / 2], u2, dinv, q, SCALE2);
        }
        for (; k < cnt; k += TPB / 2)
            agg_edge(u.acc, eb[k], u2, dinv, q, SCALE2);
        __syncthreads();
        int node = j * NPB + t;
        if (t < NPB && node < n) {
            float di = dinv[node];
            const int* ar = &u.acc[t * 17];
            const float4* sp = (const float4*)(s2p12 + (size_t)node * 12);
            float4 a0 = sp[0], a1 = sp[1], a2 = sp[2];
            float sf[NC] = {a0.x, a0.y, a0.z, a0.w, a1.x, a1.y, a1.z, a1.w, a2.x, a2.y};
            float v[NC];
            float mx = -1e30f;
#pragma unroll
            for (int c = 0; c < NC; c++) {
                v[c] = sf[c] + di * ((float)ar[c] * INV2) + sb2[c];
                mx = fmaxf(mx, v[c]);
            }
            float se = 0.f;
#pragma unroll
            for (int c = 0; c < NC; c++) se += expf(v[c] - mx);
            float ls = logf(se);
            float2* op = (float2*)(out + (size_t)node * NC);
#pragma unroll
            for (int i = 0; i < 5; i++)
                op[i] = make_float2(v[2*i] - mx - ls, v[2*i+1] - mx - ls);
        }
        __syncthreads();
    }
}

// ---------------- launch ----------------

extern "C" void kernel_launch(void* const* d_in, const int* in_sizes, int n_in,
                              void* d_out, int out_size, void* d_ws, size_t ws_size,
                              hipStream_t stream) {
    const float* x    = (const float*)d_in[0];
    const int*   ei   = (const int*)d_in[1];
    const float* w10  = (const float*)d_in[2];
    const float* w11  = (const float*)d_in[3];
    const float* b1   = (const float*)d_in[4];
    const float* w20  = (const float*)d_in[5];
    const float* w21  = (const float*)d_in[6];
    const float* b2   = (const float*)d_in[7];
    float* out = (float*)d_out;

    int n = in_sizes[0] / N_FEAT;   // 100000
    int E = in_sizes[1] / 2;        // 1600000
    const int* src = ei;
    const int* dst = ei + E;

    int NB = (n + NPB - 1) >> NPB_SHIFT;   // 782

    auto align256 = [](size_t v) { return (v + 255) & ~(size_t)255; };

    size_t off = 0;
    int*   bar   = (int*)((char*)d_ws + off);   off += 256;
    int*   bcur  = (int*)((char*)d_ws + off);   off += (size_t)NB * 16 * 4;
    size_t zero_bytes = off;                    // bar + bcur zeroed
    off = align256(off);
    int*   ebuf  = (int*)((char*)d_ws + off);   off = align256(off + (size_t)NB * CAP * 4);
    float* dinv  = (float*)((char*)d_ws + off); off = align256(off + (size_t)NB * NPB * 4);
    float* s1    = (float*)((char*)d_ws + off); off = align256(off + (size_t)n * HID * 4);
    uint4* u1    = (uint4*)((char*)d_ws + off); off = align256(off + (size_t)n * 32);
    float* s2p12 = (float*)((char*)d_ws + off); off = align256(off + (size_t)n * 12 * 4);
    uint4* u2    = (uint4*)((char*)d_ws + off); off = align256(off + (size_t)n * 32);

    hipMemsetAsync(d_ws, 0, zero_bytes, stream);
    mega_kernel<<<GRID, TPB, 0, stream>>>(x, src, dst, w10, w11, b1, w20, w21, b2,
                                          n, E, NB, bar, bcur, ebuf, dinv,
                                          s1, u1, s2p12, u2, out);
}

// Round 12
// 191.016 us; speedup vs baseline: 3.8929x; 3.8929x over previous
//
#include <hip/hip_runtime.h>

#define N_FEAT 50
#define HID 16
#define NC 10
#define TPB 256

#define NPB 512          // nodes per bucket (power of 2)
#define NPB_SHIFT 9
#define CAP 10240        // edge capacity per bucket (mean 8163, huge margin)
#define BIN_VPT 32
#define BIN_CHUNK (TPB * BIN_VPT)   // 8192 edges per block -> 196 blocks
#define CSR_T 512        // threads per csr block
#define WSTR 56          // transposed weight row stride (224 B, 16-aligned)

__device__ __forceinline__ unsigned short f2bf(float f) {
    unsigned u = __float_as_uint(f);
    u += 0x7FFFu + ((u >> 16) & 1u);
    return (unsigned short)(u >> 16);
}
__device__ __forceinline__ unsigned packbf(float lo, float hi) {
    return (unsigned)f2bf(lo) | ((unsigned)f2bf(hi) << 16);
}
// accumulate 8 bf16 (packed in uint4) into acc[0..7]
__device__ __forceinline__ void acc_bf8(float* acc, uint4 m) {
    acc[0] += __uint_as_float(m.x << 16);
    acc[1] += __uint_as_float(m.x & 0xFFFF0000u);
    acc[2] += __uint_as_float(m.y << 16);
    acc[3] += __uint_as_float(m.y & 0xFFFF0000u);
    acc[4] += __uint_as_float(m.z << 16);
    acc[5] += __uint_as_float(m.z & 0xFFFF0000u);
    acc[6] += __uint_as_float(m.w << 16);
    acc[7] += __uint_as_float(m.w & 0xFFFF0000u);
}

// ---------------- binning: edges -> bucket-contiguous packed words ----------------
// word = (src << 9) | (dst & 511); bucket = dst >> 9. bcur pre-zeroed by memset.

__global__ void bin_kernel(const int* __restrict__ src, const int* __restrict__ dst, int E,
                           int* __restrict__ bcur, int* __restrict__ ebuf) {
    __shared__ int hist[256];
    __shared__ int base[256];
    int t = threadIdx.x;
    hist[t] = 0;
    __syncthreads();

    int blockBase = blockIdx.x * BIN_CHUNK;
#pragma unroll
    for (int i = 0; i < BIN_VPT; i++) {
        int e = blockBase + i * TPB + t;
        if (e < E) {
            int d = dst[e];
            atomicAdd(&hist[d >> NPB_SHIFT], 1);
        }
    }
    __syncthreads();
    int c = hist[t];
    base[t] = t * CAP + atomicAdd(&bcur[t], c);
    hist[t] = 0;
    __syncthreads();
#pragma unroll
    for (int i = 0; i < BIN_VPT; i++) {
        int e = blockBase + i * TPB + t;
        if (e < E) {
            int d = dst[e];
            int s = src[e];
            int b = d >> NPB_SHIFT;
            int off = atomicAdd(&hist[b], 1);
            int idx = base[b] + off;
            if (idx < (b + 1) * CAP)     // overflow guard (never expected)
                ebuf[idx] = (s << NPB_SHIFT) | (d & (NPB - 1));
        }
    }
}

// ---------------- per-bucket CSR build + dinv + fused node1 ----------------
// s1 = x@w1_0 (fp32, stride 16); t1s = dinv*(x@w1_1) as bf16 x16 (32 B/node)

__global__ __launch_bounds__(CSR_T)
void csr_node1_kernel(const int* __restrict__ bcur, const int* __restrict__ ebuf,
                      const float* __restrict__ x,
                      const float* __restrict__ w10, const float* __restrict__ w11,
                      int n,
                      int* __restrict__ esrcS, int2* __restrict__ rowbe,
                      float* __restrict__ dinv_g,
                      float* __restrict__ s1, uint4* __restrict__ t1s) {
    __shared__ int hist[NPB];
    __shared__ int scn[NPB];
    __shared__ int cur[NPB];
    __shared__ float swT0[HID * WSTR];   // transposed: swT[j*WSTR + i] = w[i*HID + j]
    __shared__ float swT1[HID * WSTR];
    int t = threadIdx.x;
    int b = blockIdx.x;
    int bBase = b * CAP;
    int count = bcur[b];
    if (count > CAP) count = CAP;

    hist[t] = 0;
    for (int idx = t; idx < N_FEAT * HID; idx += CSR_T) {
        int i = idx >> 4;
        int j = idx & 15;
        swT0[j * WSTR + i] = w10[idx];
        swT1[j * WSTR + i] = w11[idx];
    }
    __syncthreads();

    for (int k = t; k < count; k += CSR_T)
        atomicAdd(&hist[ebuf[bBase + k] & (NPB - 1)], 1);
    __syncthreads();

    int deg = hist[t];
    scn[t] = deg;
    __syncthreads();
    for (int off = 1; off < NPB; off <<= 1) {
        int val = scn[t];
        int add = (t >= off) ? scn[t - off] : 0;
        __syncthreads();
        scn[t] = val + add;
        __syncthreads();
    }
    int excl = scn[t] - deg;
    cur[t] = excl;
    int node = b * NPB + t;
    float di = (deg > 0) ? rsqrtf((float)deg) : 0.0f;
    if (node < n) {
        rowbe[node] = make_int2(bBase + excl, bBase + excl + deg);
        dinv_g[node] = di;
    }
    __syncthreads();

    for (int k = t; k < count; k += CSR_T) {
        int w = ebuf[bBase + k];
        int dl = w & (NPB - 1);
        int pos = atomicAdd(&cur[dl], 1);
        esrcS[bBase + pos] = w >> NPB_SHIFT;
    }

    // fused node1
    if (node >= n) return;
    float xr[N_FEAT];
    const float2* xp = (const float2*)(x + (size_t)node * N_FEAT);
#pragma unroll
    for (int i = 0; i < N_FEAT / 2; i++) {
        float2 v = xp[i];
        xr[2 * i] = v.x;
        xr[2 * i + 1] = v.y;
    }
    float so[HID], po[HID];
#pragma unroll
    for (int j = 0; j < HID; j++) {
        float a0 = 0.f, a1 = 0.f;
#pragma unroll
        for (int i = 0; i < N_FEAT; i++) {
            a0 += xr[i] * swT0[j * WSTR + i];
            a1 += xr[i] * swT1[j * WSTR + i];
        }
        so[j] = a0;
        po[j] = di * a1;
    }
    float4* s1p = (float4*)(s1 + (size_t)node * HID);
#pragma unroll
    for (int i = 0; i < 4; i++)
        s1p[i] = make_float4(so[4 * i], so[4 * i + 1], so[4 * i + 2], so[4 * i + 3]);
    t1s[(size_t)node * 2 + 0] = make_uint4(packbf(po[0], po[1]), packbf(po[2], po[3]),
                                           packbf(po[4], po[5]), packbf(po[6], po[7]));
    t1s[(size_t)node * 2 + 1] = make_uint4(packbf(po[8], po[9]), packbf(po[10], po[11]),
                                           packbf(po[12], po[13]), packbf(po[14], po[15]));
}

// ---------------- gather layer-1 + node2 fused ----------------
// 2 lanes per node (q = t&1). 8-edge unrolled main loop: each lane loads 4
// indices (scalar dwords), gathers its 4, shfl-dedups partner's 4, gathers
// those -> 8 independent 16B gathers in flight per lane.

__global__ __launch_bounds__(TPB)
void gh_n2_kernel(const int2* __restrict__ rowbe, const int* __restrict__ esrc,
                  const uint4* __restrict__ t1s,     // [n*2] uint4 (bf16 x8 halves)
                  const float4* __restrict__ s1v4,
                  const float* __restrict__ dinv,
                  const float* __restrict__ b1,
                  const float* __restrict__ w20, const float* __restrict__ w21,
                  int n,
                  float* __restrict__ s2p12, uint4* __restrict__ ps) {
    __shared__ float hsh[128 * 17];
    __shared__ float sw0[HID * NC];
    __shared__ float sw1[HID * NC];
    __shared__ float sb1[HID];
    int t = threadIdx.x;
    if (t < HID * NC) { sw0[t] = w20[t]; sw1[t] = w21[t]; }
    if (t < HID) sb1[t] = b1[t];

    int nl = t >> 1;
    int q = t & 1;
    int node = blockIdx.x * 128 + nl;
    float acc[8];
#pragma unroll
    for (int i = 0; i < 8; i++) acc[i] = 0.f;
    if (node < n) {
        int2 be = rowbe[node];
        int k = be.x;
        for (; k + 7 < be.y; k += 8) {
            int kb = k + 4 * q;
            int e0 = esrc[kb];
            int e1 = esrc[kb + 1];
            int e2 = esrc[kb + 2];
            int e3 = esrc[kb + 3];
            uint4 m0 = t1s[(size_t)e0 * 2 + q];
            uint4 m1 = t1s[(size_t)e1 * 2 + q];
            uint4 m2 = t1s[(size_t)e2 * 2 + q];
            uint4 m3 = t1s[(size_t)e3 * 2 + q];
            int p0 = __shfl_xor(e0, 1);
            int p1 = __shfl_xor(e1, 1);
            int p2 = __shfl_xor(e2, 1);
            int p3 = __shfl_xor(e3, 1);
            uint4 m4 = t1s[(size_t)p0 * 2 + q];
            uint4 m5 = t1s[(size_t)p1 * 2 + q];
            uint4 m6 = t1s[(size_t)p2 * 2 + q];
            uint4 m7 = t1s[(size_t)p3 * 2 + q];
            acc_bf8(acc, m0); acc_bf8(acc, m1); acc_bf8(acc, m2); acc_bf8(acc, m3);
            acc_bf8(acc, m4); acc_bf8(acc, m5); acc_bf8(acc, m6); acc_bf8(acc, m7);
        }
        for (; k + 3 < be.y; k += 4) {
            int ea = esrc[k + 2 * q];
            int eb = esrc[k + 2 * q + 1];
            int ec = __shfl_xor(ea, 1);
            int ed = __shfl_xor(eb, 1);
            uint4 m0 = t1s[(size_t)ea * 2 + q];
            uint4 m1 = t1s[(size_t)eb * 2 + q];
            uint4 m2 = t1s[(size_t)ec * 2 + q];
            uint4 m3 = t1s[(size_t)ed * 2 + q];
            acc_bf8(acc, m0); acc_bf8(acc, m1);
            acc_bf8(acc, m2); acc_bf8(acc, m3);
        }
        for (; k < be.y; k++) {
            uint4 m = t1s[(size_t)esrc[k] * 2 + q];
            acc_bf8(acc, m);
        }
    }
    float* hp = &hsh[nl * 17 + q * 8];
#pragma unroll
    for (int i = 0; i < 8; i++) hp[i] = acc[i];
    __syncthreads();

    if (t < 128) {
        int node2 = blockIdx.x * 128 + t;
        if (node2 < n) {
            float di = dinv[node2];
            float h[HID];
            const float* ar = &hsh[t * 17];
#pragma unroll
            for (int i = 0; i < 4; i++) {
                float4 sv = s1v4[(size_t)node2 * 4 + i];
                h[4 * i + 0] = fmaxf(sv.x + di * ar[4 * i + 0] + sb1[4 * i + 0], 0.f);
                h[4 * i + 1] = fmaxf(sv.y + di * ar[4 * i + 1] + sb1[4 * i + 1], 0.f);
                h[4 * i + 2] = fmaxf(sv.z + di * ar[4 * i + 2] + sb1[4 * i + 2], 0.f);
                h[4 * i + 3] = fmaxf(sv.w + di * ar[4 * i + 3] + sb1[4 * i + 3], 0.f);
            }
            float so[12], po[NC];
#pragma unroll
            for (int c = 0; c < NC; c++) {
                float a0 = 0.f, a1 = 0.f;
#pragma unroll
                for (int j = 0; j < HID; j++) {
                    a0 += h[j] * sw0[j * NC + c];
                    a1 += h[j] * sw1[j * NC + c];
                }
                so[c] = a0;
                po[c] = di * a1;
            }
            so[10] = 0.f; so[11] = 0.f;
            float4* s2v = (float4*)(s2p12 + (size_t)node2 * 12);
#pragma unroll
            for (int i = 0; i < 3; i++)
                s2v[i] = make_float4(so[4 * i], so[4 * i + 1], so[4 * i + 2], so[4 * i + 3]);
            ps[(size_t)node2 * 2 + 0] = make_uint4(packbf(po[0], po[1]), packbf(po[2], po[3]),
                                                   packbf(po[4], po[5]), packbf(po[6], po[7]));
            ps[(size_t)node2 * 2 + 1] = make_uint4(packbf(po[8], po[9]), 0u, 0u, 0u);
        }
    }
}

// ---------------- gather layer-2 + log_softmax fused ----------------

__global__ __launch_bounds__(TPB)
void gv_final_kernel(const int2* __restrict__ rowbe, const int* __restrict__ esrc,
                     const uint4* __restrict__ ps,
                     const float4* __restrict__ s2v4,
                     const float* __restrict__ dinv,
                     const float* __restrict__ b2,
                     int n,
                     float* __restrict__ out) {
    __shared__ float vsh[128 * 17];
    __shared__ float sb2[NC];
    int t = threadIdx.x;
    if (t < NC) sb2[t] = b2[t];

    int nl = t >> 1;
    int q = t & 1;
    int node = blockIdx.x * 128 + nl;
    float acc[8];
#pragma unroll
    for (int i = 0; i < 8; i++) acc[i] = 0.f;
    if (node < n) {
        int2 be = rowbe[node];
        int k = be.x;
        for (; k + 7 < be.y; k += 8) {
            int kb = k + 4 * q;
            int e0 = esrc[kb];
            int e1 = esrc[kb + 1];
            int e2 = esrc[kb + 2];
            int e3 = esrc[kb + 3];
            uint4 m0 = ps[(size_t)e0 * 2 + q];
            uint4 m1 = ps[(size_t)e1 * 2 + q];
            uint4 m2 = ps[(size_t)e2 * 2 + q];
            uint4 m3 = ps[(size_t)e3 * 2 + q];
            int p0 = __shfl_xor(e0, 1);
            int p1 = __shfl_xor(e1, 1);
            int p2 = __shfl_xor(e2, 1);
            int p3 = __shfl_xor(e3, 1);
            uint4 m4 = ps[(size_t)p0 * 2 + q];
            uint4 m5 = ps[(size_t)p1 * 2 + q];
            uint4 m6 = ps[(size_t)p2 * 2 + q];
            uint4 m7 = ps[(size_t)p3 * 2 + q];
            acc_bf8(acc, m0); acc_bf8(acc, m1); acc_bf8(acc, m2); acc_bf8(acc, m3);
            acc_bf8(acc, m4); acc_bf8(acc, m5); acc_bf8(acc, m6); acc_bf8(acc, m7);
        }
        for (; k + 3 < be.y; k += 4) {
            int ea = esrc[k + 2 * q];
            int eb = esrc[k + 2 * q + 1];
            int ec = __shfl_xor(ea, 1);
            int ed = __shfl_xor(eb, 1);
            uint4 m0 = ps[(size_t)ea * 2 + q];
            uint4 m1 = ps[(size_t)eb * 2 + q];
            uint4 m2 = ps[(size_t)ec * 2 + q];
            uint4 m3 = ps[(size_t)ed * 2 + q];
            acc_bf8(acc, m0); acc_bf8(acc, m1);
            acc_bf8(acc, m2); acc_bf8(acc, m3);
        }
        for (; k < be.y; k++) {
            uint4 m = ps[(size_t)esrc[k] * 2 + q];
            acc_bf8(acc, m);
        }
    }
    float* vp = &vsh[nl * 17 + q * 8];
#pragma unroll
    for (int i = 0; i < 8; i++) vp[i] = acc[i];
    __syncthreads();

    if (t < 128) {
        int node2 = blockIdx.x * 128 + t;
        if (node2 < n) {
            float di = dinv[node2];
            float4 a0 = s2v4[(size_t)node2 * 3 + 0];
            float4 a1 = s2v4[(size_t)node2 * 3 + 1];
            float4 a2 = s2v4[(size_t)node2 * 3 + 2];
            float sf[NC] = {a0.x, a0.y, a0.z, a0.w, a1.x, a1.y, a1.z, a1.w, a2.x, a2.y};
            const float* ar = &vsh[t * 17];
            float v[NC];
            float mx = -1e30f;
#pragma unroll
            for (int c = 0; c < NC; c++) {
                v[c] = sf[c] + di * ar[c] + sb2[c];
                mx = fmaxf(mx, v[c]);
            }
            float se = 0.f;
#pragma unroll
            for (int c = 0; c < NC; c++) se += expf(v[c] - mx);
            float ls = logf(se);
            float2* op = (float2*)(out + (size_t)node2 * NC);
#pragma unroll
            for (int i = 0; i < 5; i++)
                op[i] = make_float2(v[2 * i] - mx - ls, v[2 * i + 1] - mx - ls);
        }
    }
}

// ---------------- launch ----------------

extern "C" void kernel_launch(void* const* d_in, const int* in_sizes, int n_in,
                              void* d_out, int out_size, void* d_ws, size_t ws_size,
                              hipStream_t stream) {
    const float* x    = (const float*)d_in[0];
    const int*   ei   = (const int*)d_in[1];
    const float* w10  = (const float*)d_in[2];
    const float* w11  = (const float*)d_in[3];
    const float* b1   = (const float*)d_in[4];
    const float* w20  = (const float*)d_in[5];
    const float* w21  = (const float*)d_in[6];
    const float* b2   = (const float*)d_in[7];
    float* out = (float*)d_out;

    int n = in_sizes[0] / N_FEAT;   // 100000
    int E = in_sizes[1] / 2;        // 1600000
    const int* src = ei;
    const int* dst = ei + E;

    int NB = (n + NPB - 1) >> NPB_SHIFT;   // 196

    auto align256 = [](size_t v) { return (v + 255) & ~(size_t)255; };

    size_t off = 0;
    int*   bcur  = (int*)((char*)d_ws + off);   off = align256(off + 256 * 4);
    int*   ebuf  = (int*)((char*)d_ws + off);   off = align256(off + (size_t)NB * CAP * 4);
    int*   esrcS = (int*)((char*)d_ws + off);   off = align256(off + (size_t)NB * CAP * 4);
    int2*  rowbe = (int2*)((char*)d_ws + off);  off = align256(off + (size_t)n * 8);
    float* dinv  = (float*)((char*)d_ws + off); off = align256(off + (size_t)n * 4);
    float* s1    = (float*)((char*)d_ws + off); off = align256(off + (size_t)n * HID * 4);
    uint4* t1s   = (uint4*)((char*)d_ws + off); off = align256(off + (size_t)n * 32);
    float* s2p12 = (float*)((char*)d_ws + off); off = align256(off + (size_t)n * 12 * 4);
    uint4* ps    = (uint4*)((char*)d_ws + off); off = align256(off + (size_t)n * 32);

    hipMemsetAsync(bcur, 0, 256 * 4, stream);
    bin_kernel<<<(E + BIN_CHUNK - 1) / BIN_CHUNK, TPB, 0, stream>>>(src, dst, E, bcur, ebuf);
    csr_node1_kernel<<<NB, CSR_T, 0, stream>>>(bcur, ebuf, x, w10, w11, n,
                                               esrcS, rowbe, dinv, s1, t1s);
    gh_n2_kernel<<<(n + 127) / 128, TPB, 0, stream>>>(rowbe, esrcS, t1s,
                                                      (const float4*)s1, dinv, b1, w20, w21,
                                                      n, s2p12, ps);
    gv_final_kernel<<<(n + 127) / 128, TPB, 0, stream>>>(rowbe, esrcS, ps,
                                                         (const float4*)s2p12, dinv, b2,
                                                         n, out);
}